// Round 1
// baseline (605.868 us; speedup 1.0000x reference)
//
#include <hip/hip_runtime.h>

#define S_     264
#define BL_    256
#define TWO_S  528
#define TWO_BL 512
#define B_     512
#define V_     128
#define NQ     392   // S + V

// ---------------------------------------------------------------------------
// Kernel 1: one block per (batch, psi). Single pass over Psi[b] in row-pairs.
// Computes contrib[(b*2+psi)][s] = coefY*mv(A,y)[s] + coefS*mv(A,sql)[s]
// where mv(A,w)[s] = c[s]*t_w[s] + s[s]*t_w[S+s],  t_w = Psi^T (Px .* w_ext).
// ---------------------------------------------------------------------------
__global__ __launch_bounds__(256) void k_psi(
    const float* __restrict__ x_mag, const float* __restrict__ x_phase,
    const float* __restrict__ y_e, const float* __restrict__ y_o,
    const float* __restrict__ Psi_e, const float* __restrict__ Psi_o,
    const float* __restrict__ d1, const float* __restrict__ d2,
    const float* __restrict__ d4,
    float* __restrict__ contrib)
{
    const int tid = threadIdx.x;
    const int b   = blockIdx.x >> 1;
    const int psi = blockIdx.x & 1;
    const float* Psi = psi ? Psi_o : Psi_e;
    const float* yv  = psi ? y_o  : y_e;
    const float coefY = psi ? -d2[0] : -d1[0];
    const float coefS = psi ?  d4[0] :  d2[0];

    __shared__ float  xs[TWO_S];
    __shared__ float  cs[S_], sn[S_];
    __shared__ float  ys[BL_];
    __shared__ float4 Plo4[8 * 132];   // 8 lo rows  (m .. m+7)     528 f each
    __shared__ float4 Phi4[8 * 132];   // 8 hi rows  (m+256 ..)
    __shared__ float  av[8], bv[8];
    __shared__ float  tyf[TWO_S], tsf[TWO_S];

    float* Plo = (float*)Plo4;
    float* Phi = (float*)Phi4;

    for (int s = tid; s < S_; s += 256) {
        float mag = x_mag[(size_t)b * S_ + s];
        float ph  = x_phase[(size_t)b * S_ + s];
        float c = cosf(ph), si = sinf(ph);
        cs[s] = c; sn[s] = si;
        xs[s]      = mag * c;
        xs[S_ + s] = mag * si;
    }
    ys[tid] = yv[(size_t)b * BL_ + tid];
    __syncthreads();

    float ty0 = 0.f, ty1 = 0.f, ty2 = 0.f;
    float ts0 = 0.f, ts1 = 0.f, ts2 = 0.f;

    const float4* Pg = (const float4*)(Psi + (size_t)b * TWO_BL * TWO_S);
    const int wave = tid >> 6, lane = tid & 63;

    for (int chunk = 0; chunk < 32; ++chunk) {
        const int m0 = chunk * 8;
        // ---- stage 8 lo rows + 8 hi rows (each row = 132 float4, contiguous)
        const float4* glo = Pg + (size_t)m0 * 132;
        const float4* ghi = Pg + (size_t)(m0 + BL_) * 132;
        for (int i = tid; i < 1056; i += 256) {
            Plo4[i] = glo[i];
            Phi4[i] = ghi[i];
        }
        __syncthreads();
        // ---- dots: a[r] = Plo[r].xs, b[r] = Phi[r].xs  (16 dots, 4 per wave)
        for (int rr = wave; rr < 16; rr += 4) {
            const float* rowp = (rr < 8) ? (Plo + rr * TWO_S)
                                         : (Phi + (rr - 8) * TWO_S);
            float p = 0.f;
            for (int col = lane; col < TWO_S; col += 64)
                p += rowp[col] * xs[col];
            #pragma unroll
            for (int off = 32; off; off >>= 1)
                p += __shfl_xor(p, off);
            if (lane == 0) {
                if (rr < 8) av[rr] = p; else bv[rr - 8] = p;
            }
        }
        __syncthreads();
        // ---- accumulate t_y, t_sql (thread owns cols tid, tid+256, [tid+512])
        #pragma unroll
        for (int r = 0; r < 8; ++r) {
            const float aa = av[r], bb = bv[r];
            const float yy = ys[m0 + r];
            const float sq = aa * aa + bb * bb;
            const float cyl = aa * yy, cyh = bb * yy;
            const float csl = aa * sq, csh = bb * sq;
            const int rb = r * TWO_S;
            float pl0 = Plo[rb + tid],        ph0 = Phi[rb + tid];
            ty0 += pl0 * cyl + ph0 * cyh;
            ts0 += pl0 * csl + ph0 * csh;
            float pl1 = Plo[rb + tid + 256],  ph1 = Phi[rb + tid + 256];
            ty1 += pl1 * cyl + ph1 * cyh;
            ts1 += pl1 * csl + ph1 * csh;
            if (tid < 16) {
                float pl2 = Plo[rb + tid + 512], ph2 = Phi[rb + tid + 512];
                ty2 += pl2 * cyl + ph2 * cyh;
                ts2 += pl2 * csl + ph2 * csh;
            }
        }
        __syncthreads();
    }

    tyf[tid] = ty0; tyf[tid + 256] = ty1;
    tsf[tid] = ts0; tsf[tid + 256] = ts1;
    if (tid < 16) { tyf[tid + 512] = ty2; tsf[tid + 512] = ts2; }
    __syncthreads();

    float* outp = contrib + (size_t)(b * 2 + psi) * S_;
    for (int s = tid; s < S_; s += 256) {
        float mvy = cs[s] * tyf[s] + sn[s] * tyf[S_ + s];
        float mvs = cs[s] * tsf[s] + sn[s] * tsf[S_ + s];
        outp[s] = coefY * mvy + coefS * mvs;
    }
}

// ---------------------------------------------------------------------------
// Kernel 2: build cat = [q, v]  (512 x 392); q = mag + contrib_e + contrib_o
// ---------------------------------------------------------------------------
__global__ void k_cat(const float* __restrict__ x_mag, const float* __restrict__ v,
                      const float* __restrict__ contrib, float* __restrict__ cat)
{
    int idx = blockIdx.x * 256 + threadIdx.x;
    if (idx >= B_ * NQ) return;
    int b = idx / NQ, j = idx % NQ;
    float val;
    if (j < S_) {
        val = x_mag[(size_t)b * S_ + j]
            + contrib[(size_t)(b * 2) * S_ + j]
            + contrib[(size_t)(b * 2 + 1) * S_ + j];
    } else {
        val = v[(size_t)b * V_ + (j - S_)];
    }
    cat[idx] = val;
}

// ---------------------------------------------------------------------------
// Generic fp32 tiled GEMM: out = [act](A @ W^T + bias [+ addend])
// A: M x K row-major, W: N x K row-major. Block tile 32x64, thread 4x2.
// ---------------------------------------------------------------------------
template<bool RELU, bool ADD>
__global__ __launch_bounds__(256) void k_gemm(
    const float* __restrict__ A, const float* __restrict__ W,
    const float* __restrict__ bias, const float* __restrict__ addend,
    float* __restrict__ out, int M, int N, int K)
{
    const int tid  = threadIdx.x;
    const int m0   = blockIdx.x * 32;
    const int n0   = blockIdx.y * 64;
    const int tcol = tid & 31;   // 0..31 -> 2 cols each
    const int trow = tid >> 5;   // 0..7  -> 4 rows each (stride 8)

    __shared__ float As[32][32];
    __shared__ float Ws[64][33];

    float acc[4][2] = {};

    for (int kc = 0; kc < K; kc += 32) {
        // stage A (32x32 = 256 float4, one per thread)
        {
            int r = tid >> 3, j4 = (tid & 7) * 4;
            int gk = kc + j4;
            const float* ap = A + (size_t)(m0 + r) * K + gk;
            if (gk + 3 < K) {
                *(float4*)&As[r][j4] = *(const float4*)ap;
            } else {
                for (int jj = 0; jj < 4; ++jj)
                    As[r][j4 + jj] = (gk + jj < K) ? ap[jj] : 0.f;
            }
        }
        // stage W (64x32 = 512 float4, two per thread) into padded [64][33]
        for (int i = tid; i < 512; i += 256) {
            int r = i >> 3, j4 = (i & 7) * 4;
            int gk = kc + j4;
            int wrow = n0 + r;
            float vv[4] = {0.f, 0.f, 0.f, 0.f};
            if (wrow < N) {
                const float* wp = W + (size_t)wrow * K + gk;
                if (gk + 3 < K) {
                    float4 t = *(const float4*)wp;
                    vv[0] = t.x; vv[1] = t.y; vv[2] = t.z; vv[3] = t.w;
                } else {
                    for (int jj = 0; jj < 4; ++jj)
                        if (gk + jj < K) vv[jj] = wp[jj];
                }
            }
            for (int jj = 0; jj < 4; ++jj) Ws[r][j4 + jj] = vv[jj];
        }
        __syncthreads();

        #pragma unroll
        for (int j = 0; j < 32; ++j) {
            float w0 = Ws[tcol * 2][j], w1 = Ws[tcol * 2 + 1][j];
            #pragma unroll
            for (int rr = 0; rr < 4; ++rr) {
                float a = As[trow + rr * 8][j];
                acc[rr][0] += a * w0;
                acc[rr][1] += a * w1;
            }
        }
        __syncthreads();
    }

    #pragma unroll
    for (int rr = 0; rr < 4; ++rr) {
        int row = m0 + trow + rr * 8;
        #pragma unroll
        for (int cc = 0; cc < 2; ++cc) {
            int col = n0 + tcol * 2 + cc;
            if (col < N) {
                float vOut = acc[rr][cc] + bias[col];
                if (ADD) vOut += addend[(size_t)row * N + col];
                if (RELU) vOut = fmaxf(vOut, 0.f);
                out[(size_t)row * N + col] = vOut;
            }
        }
    }
}

// ---------------------------------------------------------------------------
// Kernel 4: copy x_mag to out[0], softmax(oh.reshape(B,S,4)) @ MAPP -> out[1]
// ---------------------------------------------------------------------------
__global__ void k_final(const float* __restrict__ x_mag,
                        const float* __restrict__ oh_new,
                        float* __restrict__ out0)
{
    int idx = blockIdx.x * 256 + threadIdx.x;
    if (idx >= B_ * S_) return;
    out0[idx] = x_mag[idx];
    int b = idx / S_, s = idx % S_;
    const float* p = oh_new + (size_t)b * (S_ * 4) + s * 4;
    float a0 = p[0], a1 = p[1], a2 = p[2], a3 = p[3];
    float m  = fmaxf(fmaxf(a0, a1), fmaxf(a2, a3));
    float e0 = expf(a0 - m), e1 = expf(a1 - m), e2 = expf(a2 - m), e3 = expf(a3 - m);
    float sum = e0 + e1 + e2 + e3;
    float sym = (0.5f * e0 + 1.0f * e1 + 1.5f * e2 + 2.0f * e3) / sum;
    out0[B_ * S_ + idx] = sym;
}

// ---------------------------------------------------------------------------
extern "C" void kernel_launch(void* const* d_in, const int* in_sizes, int n_in,
                              void* d_out, int out_size, void* d_ws, size_t ws_size,
                              hipStream_t stream)
{
    const float* x_mag    = (const float*)d_in[1];
    const float* x_mag_oh = (const float*)d_in[2];
    const float* v        = (const float*)d_in[3];
    const float* x_phase  = (const float*)d_in[4];
    const float* y_e      = (const float*)d_in[5];
    const float* y_o      = (const float*)d_in[6];
    const float* Psi_e    = (const float*)d_in[7];
    const float* Psi_o    = (const float*)d_in[8];
    const float* W1       = (const float*)d_in[9];
    const float* b1       = (const float*)d_in[10];
    const float* W2       = (const float*)d_in[11];
    const float* b2       = (const float*)d_in[12];
    const float* W3       = (const float*)d_in[13];
    const float* b3       = (const float*)d_in[14];
    const float* d1       = (const float*)d_in[15];
    const float* d2       = (const float*)d_in[16];
    const float* d4       = (const float*)d_in[18];   // d3 (d_in[17]) unused

    float* ws      = (float*)d_ws;
    float* contrib = ws;                         // 1024 * 264
    float* cat     = contrib + 1024 * S_;        // 512 * 392
    float* z       = cat + B_ * NQ;              // 512 * 1024

    float* out0   = (float*)d_out;               // 2*512*264 (x_mag_new)
    float* out_oh = out0 + 2 * B_ * S_;          // 512*1056  (x_mag_oh_new)
    float* out_v  = out_oh + B_ * (S_ * 4);      // 512*128   (v_new)

    k_psi<<<dim3(B_ * 2), dim3(256), 0, stream>>>(
        x_mag, x_phase, y_e, y_o, Psi_e, Psi_o, d1, d2, d4, contrib);

    k_cat<<<dim3((B_ * NQ + 255) / 256), dim3(256), 0, stream>>>(
        x_mag, v, contrib, cat);

    k_gemm<true,  false><<<dim3(16, 16), dim3(256), 0, stream>>>(
        cat, W1, b1, nullptr, z, B_, 1024, NQ);

    k_gemm<false, true><<<dim3(16, 17), dim3(256), 0, stream>>>(
        z, W2, b2, x_mag_oh, out_oh, B_, S_ * 4, 1024);

    k_gemm<false, true><<<dim3(16, 2), dim3(256), 0, stream>>>(
        z, W3, b3, v, out_v, B_, V_, 1024);

    k_final<<<dim3((B_ * S_ + 255) / 256), dim3(256), 0, stream>>>(
        x_mag, out_oh, out0);
}

// Round 2
// 314.124 us; speedup vs baseline: 1.9288x; 1.9288x over previous
//
#include <hip/hip_runtime.h>

#define S_     264
#define BL_    256
#define TWO_S  528
#define TWO_BL 512
#define B_     512
#define V_     128
#define NQ     392   // S + V
#define Z_     1024
#define N2_    1056  // S*4
#define NTOT   1184  // N2 + V

// ---------------------------------------------------------------------------
// Kernel 1: one block per (batch, psi). Register-resident single pass.
// Each wave processes row-pairs (m, m+256); lanes hold row fragments in
// registers, butterfly-reduce the two dots, then accumulate t_y / t_sql into
// per-lane register accumulators. No __syncthreads in the main loop.
// ---------------------------------------------------------------------------
__global__ __launch_bounds__(256, 4) void k_psi(
    const float* __restrict__ x_mag, const float* __restrict__ x_phase,
    const float* __restrict__ y_e, const float* __restrict__ y_o,
    const float* __restrict__ Psi_e, const float* __restrict__ Psi_o,
    const float* __restrict__ d1, const float* __restrict__ d2,
    const float* __restrict__ d4,
    float* __restrict__ contrib)
{
    const int tid = threadIdx.x;
    const int b   = blockIdx.x >> 1;
    const int psi = blockIdx.x & 1;
    const float* Psi = psi ? Psi_o : Psi_e;
    const float* yv  = psi ? y_o  : y_e;
    const float coefY = psi ? -d2[0] : -d1[0];
    const float coefS = psi ?  d4[0] :  d2[0];

    __shared__ float4 xs4s[132];                 // x = [mag*c, mag*s]
    __shared__ float  cs[S_], sn[S_];
    __shared__ float  ys[BL_];
    __shared__ float4 redTy4[4][132];
    __shared__ float4 redTs4[4][132];

    float* xs = (float*)xs4s;

    for (int s = tid; s < S_; s += 256) {
        float mag = x_mag[(size_t)b * S_ + s];
        float ph  = x_phase[(size_t)b * S_ + s];
        float c = cosf(ph), si = sinf(ph);
        cs[s] = c; sn[s] = si;
        xs[s]      = mag * c;
        xs[S_ + s] = mag * si;
    }
    ys[tid] = yv[(size_t)b * BL_ + tid];
    __syncthreads();

    const int wave = tid >> 6, lane = tid & 63;
    const float4 f4z = {0.f, 0.f, 0.f, 0.f};

    // per-lane x fragments (fixed column ownership)
    float4 x0 = xs4s[lane];
    float4 x1 = xs4s[lane + 64];
    float4 x2 = (lane < 4) ? xs4s[lane + 128] : f4z;

    float4 ty0 = f4z, ty1 = f4z, ty2 = f4z;
    float4 ts0 = f4z, ts1 = f4z, ts2 = f4z;

    const float4* Pg = (const float4*)(Psi + (size_t)b * TWO_BL * TWO_S);

    // prefetch first pair
    int pair = wave;
    float4 l0, l1, l2 = f4z, h0, h1, h2 = f4z;
    {
        const float4* rl = Pg + (size_t)pair * 132;
        const float4* rh = rl + (size_t)BL_ * 132;
        l0 = rl[lane]; l1 = rl[lane + 64];
        h0 = rh[lane]; h1 = rh[lane + 64];
        if (lane < 4) { l2 = rl[lane + 128]; h2 = rh[lane + 128]; }
    }

    while (pair < BL_) {
        const int nxt = pair + 4;
        float4 nl0 = f4z, nl1 = f4z, nl2 = f4z;
        float4 nh0 = f4z, nh1 = f4z, nh2 = f4z;
        if (nxt < BL_) {
            const float4* rl = Pg + (size_t)nxt * 132;
            const float4* rh = rl + (size_t)BL_ * 132;
            nl0 = rl[lane]; nl1 = rl[lane + 64];
            nh0 = rh[lane]; nh1 = rh[lane + 64];
            if (lane < 4) { nl2 = rl[lane + 128]; nh2 = rh[lane + 128]; }
        }

        float a  = l0.x*x0.x + l0.y*x0.y + l0.z*x0.z + l0.w*x0.w
                 + l1.x*x1.x + l1.y*x1.y + l1.z*x1.z + l1.w*x1.w
                 + l2.x*x2.x + l2.y*x2.y + l2.z*x2.z + l2.w*x2.w;
        float bb = h0.x*x0.x + h0.y*x0.y + h0.z*x0.z + h0.w*x0.w
                 + h1.x*x1.x + h1.y*x1.y + h1.z*x1.z + h1.w*x1.w
                 + h2.x*x2.x + h2.y*x2.y + h2.z*x2.z + h2.w*x2.w;
        #pragma unroll
        for (int off = 32; off; off >>= 1) {
            a  += __shfl_xor(a, off);
            bb += __shfl_xor(bb, off);
        }

        const float yy  = ys[pair];
        const float sq  = a * a + bb * bb;
        const float cyl = a * yy, cyh = bb * yy;
        const float csl = a * sq, csh = bb * sq;

        ty0.x += l0.x*cyl + h0.x*cyh; ty0.y += l0.y*cyl + h0.y*cyh;
        ty0.z += l0.z*cyl + h0.z*cyh; ty0.w += l0.w*cyl + h0.w*cyh;
        ty1.x += l1.x*cyl + h1.x*cyh; ty1.y += l1.y*cyl + h1.y*cyh;
        ty1.z += l1.z*cyl + h1.z*cyh; ty1.w += l1.w*cyl + h1.w*cyh;
        ty2.x += l2.x*cyl + h2.x*cyh; ty2.y += l2.y*cyl + h2.y*cyh;
        ty2.z += l2.z*cyl + h2.z*cyh; ty2.w += l2.w*cyl + h2.w*cyh;

        ts0.x += l0.x*csl + h0.x*csh; ts0.y += l0.y*csl + h0.y*csh;
        ts0.z += l0.z*csl + h0.z*csh; ts0.w += l0.w*csl + h0.w*csh;
        ts1.x += l1.x*csl + h1.x*csh; ts1.y += l1.y*csl + h1.y*csh;
        ts1.z += l1.z*csl + h1.z*csh; ts1.w += l1.w*csl + h1.w*csh;
        ts2.x += l2.x*csl + h2.x*csh; ts2.y += l2.y*csl + h2.y*csh;
        ts2.z += l2.z*csl + h2.z*csh; ts2.w += l2.w*csl + h2.w*csh;

        pair = nxt;
        l0 = nl0; l1 = nl1; l2 = nl2;
        h0 = nh0; h1 = nh1; h2 = nh2;
    }

    // per-wave partials -> LDS
    redTy4[wave][lane]      = ty0;  redTy4[wave][lane + 64] = ty1;
    redTs4[wave][lane]      = ts0;  redTs4[wave][lane + 64] = ts1;
    if (lane < 4) {
        redTy4[wave][lane + 128] = ty2;
        redTs4[wave][lane + 128] = ts2;
    }
    __syncthreads();

    const float* redTy = (const float*)redTy4;
    const float* redTs = (const float*)redTs4;
    float* outp = contrib + (size_t)(b * 2 + psi) * S_;
    for (int s = tid; s < S_; s += 256) {
        float tyl = 0.f, tyh = 0.f, tsl = 0.f, tsh = 0.f;
        #pragma unroll
        for (int w = 0; w < 4; ++w) {
            tyl += redTy[w * TWO_S + s];
            tyh += redTy[w * TWO_S + S_ + s];
            tsl += redTs[w * TWO_S + s];
            tsh += redTs[w * TWO_S + S_ + s];
        }
        float mvy = cs[s] * tyl + sn[s] * tyh;
        float mvs = cs[s] * tsl + sn[s] * tsh;
        outp[s] = coefY * mvy + coefS * mvs;
    }
}

// ---------------------------------------------------------------------------
// GEMM1 (fused cat): z = relu([q, v] @ W1^T + b1)
// q = x_mag + contrib_e + contrib_o. Tile 32x64, thread 2x4, K-chunk 16.
// LDS is k-major so compute reads are float4.
// ---------------------------------------------------------------------------
__global__ __launch_bounds__(256) void k_gemm1(
    const float* __restrict__ x_mag, const float* __restrict__ contrib,
    const float* __restrict__ v, const float* __restrict__ W1,
    const float* __restrict__ b1, float* __restrict__ z)
{
    const int tid = threadIdx.x;
    const int m0  = blockIdx.x * 32;
    const int n0  = blockIdx.y * 64;
    const int tr  = (tid >> 4) & 1 ? 0 : 0; // placeholder (unused)
    const int trow = ((tid >> 4)) * 2;      // 0..30, 2 rows per thread
    const int tcol = (tid & 15) * 4;        // 0..60, 4 cols per thread

    __shared__ float As[16][36];   // As[k][r], r stride 36 (16B-aligned rows)
    __shared__ float Ws[16][68];   // Ws[k][c]

    float acc[2][4] = {};

    const int kr  = tid >> 2;        // 0..63
    const int kk4 = (tid & 3) * 4;   // 0,4,8,12

    for (int kc = 0; kc < NQ; kc += 16) {
        // ---- stage A (cat built on the fly): rows m0..m0+31
        if (tid < 128) {
            const int arow = m0 + kr;          // kr 0..31
            const int gk = kc + kk4;
            float4 vv = {0.f, 0.f, 0.f, 0.f};
            if (gk < NQ) {
                if (gk + 3 < S_) {
                    float4 xm = *(const float4*)&x_mag[(size_t)arow * S_ + gk];
                    float4 ce = *(const float4*)&contrib[(size_t)(arow * 2) * S_ + gk];
                    float4 co = *(const float4*)&contrib[(size_t)(arow * 2 + 1) * S_ + gk];
                    vv.x = xm.x + ce.x + co.x; vv.y = xm.y + ce.y + co.y;
                    vv.z = xm.z + ce.z + co.z; vv.w = xm.w + ce.w + co.w;
                } else if (gk >= S_) {
                    vv = *(const float4*)&v[(size_t)arow * V_ + (gk - S_)];
                }
            }
            As[kk4 + 0][kr] = vv.x; As[kk4 + 1][kr] = vv.y;
            As[kk4 + 2][kr] = vv.z; As[kk4 + 3][kr] = vv.w;
        }
        // ---- stage W: cols n0..n0+63
        {
            const int wrow = n0 + kr;
            const int gk = kc + kk4;
            float4 vv = {0.f, 0.f, 0.f, 0.f};
            if (gk + 3 < NQ) {
                vv = *(const float4*)&W1[(size_t)wrow * NQ + gk];
            } else if (gk < NQ) {
                const float* wp = W1 + (size_t)wrow * NQ + gk;
                vv.x = wp[0];
                if (gk + 1 < NQ) vv.y = wp[1];
                if (gk + 2 < NQ) vv.z = wp[2];
            }
            Ws[kk4 + 0][kr] = vv.x; Ws[kk4 + 1][kr] = vv.y;
            Ws[kk4 + 2][kr] = vv.z; Ws[kk4 + 3][kr] = vv.w;
        }
        __syncthreads();

        #pragma unroll
        for (int k = 0; k < 16; ++k) {
            float2 a2 = *(const float2*)&As[k][trow];
            float4 w4 = *(const float4*)&Ws[k][tcol];
            acc[0][0] += a2.x * w4.x; acc[0][1] += a2.x * w4.y;
            acc[0][2] += a2.x * w4.z; acc[0][3] += a2.x * w4.w;
            acc[1][0] += a2.y * w4.x; acc[1][1] += a2.y * w4.y;
            acc[1][2] += a2.y * w4.z; acc[1][3] += a2.y * w4.w;
        }
        __syncthreads();
    }

    #pragma unroll
    for (int i = 0; i < 2; ++i) {
        const int row = m0 + trow + i;
        const int col = n0 + tcol;
        float4 r;
        r.x = fmaxf(acc[i][0] + b1[col + 0], 0.f);
        r.y = fmaxf(acc[i][1] + b1[col + 1], 0.f);
        r.z = fmaxf(acc[i][2] + b1[col + 2], 0.f);
        r.w = fmaxf(acc[i][3] + b1[col + 3], 0.f);
        *(float4*)&z[(size_t)row * Z_ + col] = r;
    }
}

// ---------------------------------------------------------------------------
// GEMM23 (fused): [out_oh | out_v] = z @ [W2;W3]^T + [b2;b3] + [oh | v]
// Tile 32x64 over virtual N = 1184. K = 1024.
// ---------------------------------------------------------------------------
__global__ __launch_bounds__(256) void k_gemm23(
    const float* __restrict__ z,
    const float* __restrict__ W2, const float* __restrict__ b2,
    const float* __restrict__ oh,
    const float* __restrict__ W3, const float* __restrict__ b3,
    const float* __restrict__ v,
    float* __restrict__ out_oh, float* __restrict__ out_v)
{
    const int tid = threadIdx.x;
    const int m0  = blockIdx.x * 32;
    const int n0  = blockIdx.y * 64;
    const int trow = (tid >> 4) * 2;
    const int tcol = (tid & 15) * 4;

    __shared__ float As[16][36];
    __shared__ float Ws[16][68];

    float acc[2][4] = {};

    const int kr  = tid >> 2;
    const int kk4 = (tid & 3) * 4;

    for (int kc = 0; kc < Z_; kc += 16) {
        if (tid < 128) {
            const int arow = m0 + kr;
            float4 vv = *(const float4*)&z[(size_t)arow * Z_ + kc + kk4];
            As[kk4 + 0][kr] = vv.x; As[kk4 + 1][kr] = vv.y;
            As[kk4 + 2][kr] = vv.z; As[kk4 + 3][kr] = vv.w;
        }
        {
            const int wrow = n0 + kr;
            float4 vv = {0.f, 0.f, 0.f, 0.f};
            if (wrow < NTOT) {
                const float* wp = (wrow < N2_)
                    ? (W2 + (size_t)wrow * Z_)
                    : (W3 + (size_t)(wrow - N2_) * Z_);
                vv = *(const float4*)&wp[kc + kk4];
            }
            Ws[kk4 + 0][kr] = vv.x; Ws[kk4 + 1][kr] = vv.y;
            Ws[kk4 + 2][kr] = vv.z; Ws[kk4 + 3][kr] = vv.w;
        }
        __syncthreads();

        #pragma unroll
        for (int k = 0; k < 16; ++k) {
            float2 a2 = *(const float2*)&As[k][trow];
            float4 w4 = *(const float4*)&Ws[k][tcol];
            acc[0][0] += a2.x * w4.x; acc[0][1] += a2.x * w4.y;
            acc[0][2] += a2.x * w4.z; acc[0][3] += a2.x * w4.w;
            acc[1][0] += a2.y * w4.x; acc[1][1] += a2.y * w4.y;
            acc[1][2] += a2.y * w4.z; acc[1][3] += a2.y * w4.w;
        }
        __syncthreads();
    }

    #pragma unroll
    for (int i = 0; i < 2; ++i) {
        const int row = m0 + trow + i;
        const int col = n0 + tcol;
        if (col + 3 < N2_) {
            float4 ad = *(const float4*)&oh[(size_t)row * N2_ + col];
            float4 r;
            r.x = acc[i][0] + b2[col + 0] + ad.x;
            r.y = acc[i][1] + b2[col + 1] + ad.y;
            r.z = acc[i][2] + b2[col + 2] + ad.z;
            r.w = acc[i][3] + b2[col + 3] + ad.w;
            *(float4*)&out_oh[(size_t)row * N2_ + col] = r;
        } else if (col < NTOT) {
            const int c3 = col - N2_;
            float4 ad = *(const float4*)&v[(size_t)row * V_ + c3];
            float4 r;
            r.x = acc[i][0] + b3[c3 + 0] + ad.x;
            r.y = acc[i][1] + b3[c3 + 1] + ad.y;
            r.z = acc[i][2] + b3[c3 + 2] + ad.z;
            r.w = acc[i][3] + b3[c3 + 3] + ad.w;
            *(float4*)&out_v[(size_t)row * V_ + c3] = r;
        }
    }
}

// ---------------------------------------------------------------------------
// Final: copy x_mag to out[0], softmax(oh.reshape(B,S,4)) @ MAPP -> out[1]
// ---------------------------------------------------------------------------
__global__ void k_final(const float* __restrict__ x_mag,
                        const float* __restrict__ oh_new,
                        float* __restrict__ out0)
{
    int idx = blockIdx.x * 256 + threadIdx.x;
    if (idx >= B_ * S_) return;
    out0[idx] = x_mag[idx];
    const float* p = oh_new + (size_t)idx * 4;
    float a0 = p[0], a1 = p[1], a2 = p[2], a3 = p[3];
    float m  = fmaxf(fmaxf(a0, a1), fmaxf(a2, a3));
    float e0 = expf(a0 - m), e1 = expf(a1 - m), e2 = expf(a2 - m), e3 = expf(a3 - m);
    float sum = e0 + e1 + e2 + e3;
    float sym = (0.5f * e0 + 1.0f * e1 + 1.5f * e2 + 2.0f * e3) / sum;
    out0[B_ * S_ + idx] = sym;
}

// ---------------------------------------------------------------------------
extern "C" void kernel_launch(void* const* d_in, const int* in_sizes, int n_in,
                              void* d_out, int out_size, void* d_ws, size_t ws_size,
                              hipStream_t stream)
{
    const float* x_mag    = (const float*)d_in[1];
    const float* x_mag_oh = (const float*)d_in[2];
    const float* v        = (const float*)d_in[3];
    const float* x_phase  = (const float*)d_in[4];
    const float* y_e      = (const float*)d_in[5];
    const float* y_o      = (const float*)d_in[6];
    const float* Psi_e    = (const float*)d_in[7];
    const float* Psi_o    = (const float*)d_in[8];
    const float* W1       = (const float*)d_in[9];
    const float* b1       = (const float*)d_in[10];
    const float* W2       = (const float*)d_in[11];
    const float* b2       = (const float*)d_in[12];
    const float* W3       = (const float*)d_in[13];
    const float* b3       = (const float*)d_in[14];
    const float* d1       = (const float*)d_in[15];
    const float* d2       = (const float*)d_in[16];
    const float* d4       = (const float*)d_in[18];   // d3 (d_in[17]) unused

    float* ws      = (float*)d_ws;
    float* contrib = ws;                         // 1024 * 264
    float* z       = contrib + 1024 * S_;        // 512 * 1024

    float* out0   = (float*)d_out;               // 2*512*264 (x_mag_new)
    float* out_oh = out0 + 2 * B_ * S_;          // 512*1056  (x_mag_oh_new)
    float* out_v  = out_oh + B_ * N2_;           // 512*128   (v_new)

    k_psi<<<dim3(B_ * 2), dim3(256), 0, stream>>>(
        x_mag, x_phase, y_e, y_o, Psi_e, Psi_o, d1, d2, d4, contrib);

    k_gemm1<<<dim3(16, 16), dim3(256), 0, stream>>>(
        x_mag, contrib, v, W1, b1, z);

    k_gemm23<<<dim3(16, 19), dim3(256), 0, stream>>>(
        z, W2, b2, x_mag_oh, W3, b3, v, out_oh, out_v);

    k_final<<<dim3((B_ * S_ + 255) / 256), dim3(256), 0, stream>>>(
        x_mag, out_oh, out0);
}